// Round 10
// baseline (199.085 us; speedup 1.0000x reference)
//
#include <hip/hip_runtime.h>
#include <hip/hip_bf16.h>

#define SQL  2048
#define DM   256
#define LNEPS 1e-6f
#define LOG2E    (1.44269504f)

// ---- workspace layout (byte offsets) ----
#define B_XB    (0ull)            // 4 MB  x bf16 [8192][256]
#define B_QB    (4ull<<20)        // 4 MB  q bf16 [bh][s][32]  (pre-scaled by log2e)
#define B_KB    (8ull<<20)        // 4 MB  k bf16 [bh][s][32]
#define B_VT    (12ull<<20)       // 4 MB  V^T bf16 [bh][32][2048], pre-swizzled
#define B_CTX   (16ull<<20)       // 4 MB  ctx bf16 [8192][256]
#define B_O1B   (20ull<<20)       // 4 MB  out1 bf16
#define B_MID   (32ull<<20)       // 16 MB mid bf16 [8192][1024]
#define B_WQKVT (48ull<<20)       // 384 KB bf16 [768][256]
#define B_WOT   ((48ull<<20)+(512ull<<10))  // 128 KB
#define B_W1T   (49ull<<20)       // 512 KB bf16 [1024][256]
#define B_W2T   ((49ull<<20)+(512ull<<10))  // 512 KB bf16 [256][1024]
#define B_BQKV  (50ull<<20)       // 3 KB f32
#define B_HQ    ((50ull<<20)+(64ull<<10))   // 256 KB u32 packed {1.0,hq}
#define B_HK    ((50ull<<20)+(320ull<<10))  // 256 KB u32 packed {hk,1.0}

typedef float  f32x16 __attribute__((ext_vector_type(16)));
typedef short  bf16x8 __attribute__((ext_vector_type(8)));
typedef int    i32x4  __attribute__((ext_vector_type(4)));
typedef int    i32x2  __attribute__((ext_vector_type(2)));

static __device__ __forceinline__ unsigned short bfu(float f){
    __hip_bfloat16 h = __float2bfloat16(f);
    return *reinterpret_cast<unsigned short*>(&h);
}
static __device__ __forceinline__ float b2f(unsigned short u){
    return __builtin_bit_cast(float, ((unsigned)u) << 16);
}
static __device__ __forceinline__ unsigned pk2(float a, float b){
    return (unsigned)bfu(a) | ((unsigned)bfu(b) << 16);
}
static __device__ __forceinline__ void glds16(const void* g, void* l){
    __builtin_amdgcn_global_load_lds((const __attribute__((address_space(1))) unsigned int*)g,
                                     (__attribute__((address_space(3))) unsigned int*)l, 16, 0, 0);
}

// ---------------- fused packing: weights->bf16^T, biases, x->bf16 ----------------
__global__ __launch_bounds__(256) void k_packall(
    const float* __restrict__ wq, const float* __restrict__ wk, const float* __restrict__ wv,
    const float* __restrict__ wo, const float* __restrict__ w1, const float* __restrict__ w2,
    const float* __restrict__ bq, const float* __restrict__ bk, const float* __restrict__ bv,
    const float* __restrict__ x,
    unsigned short* __restrict__ wqkvT, unsigned short* __restrict__ woT,
    unsigned short* __restrict__ w1T, unsigned short* __restrict__ w2T,
    float* __restrict__ bqkv, unsigned short* __restrict__ xb)
{
    __shared__ float tile[32][33];
    const int bid = blockIdx.x;
    const int t = threadIdx.x;
    if (bid < 768) {
        const float* W; unsigned short* Wt; int K, N, xk, yn;
        if (bid < 192) {
            int which = bid >> 6, local = bid & 63;
            W = (which == 0) ? wq : (which == 1 ? wk : wv);
            Wt = wqkvT + which * 65536; K = 256; N = 256;
            xk = local & 7; yn = local >> 3;
        } else if (bid < 256) {
            int local = bid - 192; W = wo; Wt = woT; K = 256; N = 256;
            xk = local & 7; yn = local >> 3;
        } else if (bid < 512) {
            int local = bid - 256; W = w1; Wt = w1T; K = 256; N = 1024;
            xk = local & 7; yn = local >> 3;
        } else {
            int local = bid - 512; W = w2; Wt = w2T; K = 1024; N = 256;
            xk = local & 31; yn = local >> 5;
        }
        const int tx = t & 31, ty = t >> 5;
        const int kb = xk * 32, nb = yn * 32;
#pragma unroll
        for (int i = 0; i < 32; i += 8) tile[ty + i][tx] = W[(size_t)(kb + ty + i) * N + nb + tx];
        __syncthreads();
#pragma unroll
        for (int i = 0; i < 32; i += 8) Wt[(size_t)(nb + ty + i) * K + kb + tx] = bfu(tile[tx][ty + i]);
    } else if (bid < 771) {
        int wb = bid - 768;
        const float* s = (wb == 0) ? bq : (wb == 1 ? bk : bv);
        bqkv[wb * 256 + t] = s[t];
    } else {
        const int i = (bid - 771) * 256 + t;
        float4 v = ((const float4*)x)[i];
        ushort4 o; o.x = bfu(v.x); o.y = bfu(v.y); o.z = bfu(v.z); o.w = bfu(v.w);
        ((ushort4*)xb)[i] = o;
    }
}

// ---------------- QKV GEMM (64x128 tile): q scaled by log2e; hq/hk fused; v -> VT swizzled ----------------
__global__ __launch_bounds__(256, 4) void k_qkv(
    const unsigned short* __restrict__ A, const unsigned short* __restrict__ Bt,
    const float* __restrict__ bias,
    unsigned short* __restrict__ qb, unsigned short* __restrict__ kb,
    char* __restrict__ vtg,
    unsigned int* __restrict__ hqp, unsigned int* __restrict__ hkp)
{
    __shared__ __align__(16) char As[8192];
    __shared__ __align__(16) char Bs[16384];
    const int t = threadIdx.x;
    const int lane = t & 63, w = t >> 6;
    const int lo = lane & 31, hi = lane >> 5;
    const int row0 = blockIdx.x * 64;
    const int col0 = blockIdx.y * 128;
    const int mr = (w & 1) * 32, nc = (w >> 1) * 64;
    f32x16 acc[2] = {};

    for (int kt = 0; kt < 4; ++kt) {
        const int k0 = kt * 64;
#pragma unroll
        for (int it = 0; it < 2; ++it) {
            const int idx = it * 256 + t;
            const int r = idx >> 3, g = idx & 7;
            glds16((const char*)(A + (size_t)(row0 + r) * 256 + k0) + ((g ^ (r & 7)) << 4),
                   As + idx * 16);
        }
#pragma unroll
        for (int it = 0; it < 4; ++it) {
            const int idx = it * 256 + t;
            const int r = idx >> 3, g = idx & 7;
            glds16((const char*)(Bt + (size_t)(col0 + r) * 256 + k0) + ((g ^ (r & 7)) << 4),
                   Bs + idx * 16);
        }
        __syncthreads();
        const int rA = mr + lo;
        const int rB = nc + lo;
#pragma unroll
        for (int s = 0; s < 4; ++s) {
            const int g = s * 2 + hi;
            bf16x8 fa  = *(const bf16x8*)(As + rA * 128 + ((g ^ (rA & 7)) << 4));
            bf16x8 fb0 = *(const bf16x8*)(Bs + rB * 128 + ((g ^ (rB & 7)) << 4));
            bf16x8 fb1 = *(const bf16x8*)(Bs + (rB + 32) * 128 + ((g ^ (rB & 7)) << 4));
            acc[0] = __builtin_amdgcn_mfma_f32_32x32x16_bf16(fa, fb0, acc[0], 0, 0, 0);
            acc[1] = __builtin_amdgcn_mfma_f32_32x32x16_bf16(fa, fb1, acc[1], 0, 0, 0);
        }
        __syncthreads();
    }
#pragma unroll
    for (int n = 0; n < 2; ++n) {
        const int c0 = col0 + nc + n * 32;
        const int which = c0 >> 8, h = (c0 >> 5) & 7;
        const float bv = bias[c0 + lo];
        if (which < 2) {
            unsigned short* dst = (which == 0) ? qb : kb;
            const float scl = (which == 0) ? LOG2E : 1.0f;
#pragma unroll
            for (int r = 0; r < 16; ++r) {
                const int gr = row0 + mr + (r & 3) + 8 * (r >> 2) + 4 * hi;
                const int b = gr >> 11, s = gr & 2047;
                const unsigned short u = bfu((acc[n][r] + bv) * scl);
                dst[(((size_t)(b * 8 + h)) * SQL + s) * 32 + lo] = u;
                const float vr = b2f(u);
                float sv = vr * vr;
                sv += __shfl_xor(sv, 1);  sv += __shfl_xor(sv, 2);
                sv += __shfl_xor(sv, 4);  sv += __shfl_xor(sv, 8);
                sv += __shfl_xor(sv, 16);
                if (lo == 0) {
                    const size_t gi = (size_t)(b * 8 + h) * SQL + s;
                    if (which == 0)
                        hqp[gi] = 0x3F80u | ((unsigned)bfu(-0.34657359f * sv + 0.52876637f) << 16);
                    else
                        hkp[gi] = (unsigned)bfu(-0.72134752f * sv) | 0x3F800000u;
                }
            }
        } else {
#pragma unroll
            for (int r = 0; r < 16; ++r) {
                const int gr = row0 + mr + (r & 3) + 8 * (r >> 2) + 4 * hi;
                const int b = gr >> 11, s = gr & 2047;
                const int o = s * 2;
                const int op = (o & ~0x78) | ((((o >> 3) & 15) ^ (lo & 15)) << 3);
                *(unsigned short*)(vtg + ((size_t)(b * 8 + h)) * 131072 + (size_t)lo * 4096 + op)
                    = bfu(acc[n][r] + bv);
            }
        }
    }
}

// ---------------- MFMA attention (unchanged from round 7/9) ----------------
__global__ __launch_bounds__(512, 4) void k_attn(
    const unsigned short* __restrict__ qg, const unsigned short* __restrict__ kg,
    const char* __restrict__ vtg, const unsigned int* __restrict__ hqp,
    const unsigned int* __restrict__ hkp, unsigned short* __restrict__ ctxb)
{
    __shared__ __align__(16) char smem[34048];
    char* kls = smem;
    char* vtl = smem + 16384;
    float* hks  = (float*)(smem + 32768);
    float* invs = (float*)(smem + 33792);
    float* redacc = (float*)smem;
    float* redden = (float*)(smem + 24576);

    const int t = threadIdx.x;
    const int grp = t >> 7;
    const int tl  = t & 127;
    const int lane = t & 63;
    const int w   = (t >> 6) & 1;
    const int lo = lane & 31;
    const int hi = lane >> 5;

    const int bid = (blockIdx.x & 7) * 128 + (blockIdx.x >> 3);
    const int qc = bid & 31;
    const int bh = bid >> 5;

    const int qrow = qc * 64 + w * 32 + lo;
    const unsigned short* qp = qg + ((size_t)bh * SQL + qrow) * 32;
    const bf16x8 qf0 = *(const bf16x8*)(qp + hi * 8);
    const bf16x8 qf1 = *(const bf16x8*)(qp + 16 + hi * 8);
    i32x4 b3i = {};
    if (hi == 0) b3i[0] = (int)hqp[(size_t)bh * SQL + qrow];
    const bf16x8 b3 = __builtin_bit_cast(bf16x8, b3i);

    f32x16 acc = {};
    float den = 0.f;

    const unsigned short* kbg = kg + (size_t)bh * SQL * 32;
    const char* vtb = vtg + (size_t)bh * 131072;
    const unsigned int* hkb = hkp + (size_t)bh * SQL;
    char* kd = kls + grp * 4096;
    char* vd = vtl + grp * 4096;

    for (int kt = 0; kt < 8; ++kt) {
        const int key0 = grp * 512 + kt * 64;
        {
#pragma unroll
            for (int it = 0; it < 2; ++it) {
                const int idx = it * 128 + tl;
                const int r = idx >> 2, gl = idx & 3;
                glds16((const char*)(kbg + (size_t)(key0 + r) * 32) + ((gl ^ ((r >> 1) & 3)) << 4),
                       kd + idx * 16);
                const int vrw = idx >> 3, vch = idx & 7;
                glds16(vtb + (size_t)vrw * 4096 + key0 * 2 + vch * 16, vd + idx * 16);
            }
            if (tl < 64) hks[grp * 64 + tl] = __builtin_bit_cast(float, hkb[key0 + tl]);
        }
        __syncthreads();

#pragma unroll
        for (int h2 = 0; h2 < 2; ++h2) {
            const int kb32 = h2 * 32;
            const int kA = kb32 + lo;
            const char* krow = kd + kA * 64;
            const int ksw = (kA >> 1) & 3;
            bf16x8 kf0 = *(const bf16x8*)(krow + (((0 + hi) ^ ksw) << 4));
            bf16x8 kf1 = *(const bf16x8*)(krow + (((2 + hi) ^ ksw) << 4));
            i32x4 a3i = {};
            if (hi == 0) a3i[0] = __builtin_bit_cast(int, hks[grp * 64 + kA]);
            f32x16 sc = {};
            __builtin_amdgcn_s_setprio(1);
            sc = __builtin_amdgcn_mfma_f32_32x32x16_bf16(kf0, qf0, sc, 0, 0, 0);
            sc = __builtin_amdgcn_mfma_f32_32x32x16_bf16(kf1, qf1, sc, 0, 0, 0);
            sc = __builtin_amdgcn_mfma_f32_32x32x16_bf16(
                     __builtin_bit_cast(bf16x8, a3i), b3, sc, 0, 0, 0);
            __builtin_amdgcn_s_setprio(0);
            float wv[16];
#pragma unroll
            for (int r = 0; r < 16; ++r) {
                float e1 = __builtin_amdgcn_exp2f(sc[r]);
                float ww = __builtin_amdgcn_exp2f(e1);
                den += ww;
                wv[r] = ww;
            }
            i32x4 p0; p0[0]=pk2(wv[0],wv[1]);   p0[1]=pk2(wv[2],wv[3]);
                      p0[2]=pk2(wv[4],wv[5]);   p0[3]=pk2(wv[6],wv[7]);
            i32x4 p1; p1[0]=pk2(wv[8],wv[9]);   p1[1]=pk2(wv[10],wv[11]);
                      p1[2]=pk2(wv[12],wv[13]); p1[3]=pk2(wv[14],wv[15]);
            const char* vrow = vd + lo * 128;
            const int vxor = (lo & 15) << 3;
            const int o0 = (kb32 + 4 * hi) * 2;
            const int o1 = (kb32 + 16 + 4 * hi) * 2;
            i32x2 a0 = *(const i32x2*)(vrow + (o0 ^ vxor));
            i32x2 a1 = *(const i32x2*)(vrow + ((o0 + 16) ^ vxor));
            i32x2 b0 = *(const i32x2*)(vrow + (o1 ^ vxor));
            i32x2 b1 = *(const i32x2*)(vrow + ((o1 + 16) ^ vxor));
            i32x4 vb0; vb0[0]=a0[0]; vb0[1]=a0[1]; vb0[2]=a1[0]; vb0[3]=a1[1];
            i32x4 vb1; vb1[0]=b0[0]; vb1[1]=b0[1]; vb1[2]=b1[0]; vb1[3]=b1[1];
            __builtin_amdgcn_s_setprio(1);
            acc = __builtin_amdgcn_mfma_f32_32x32x16_bf16(
                __builtin_bit_cast(bf16x8, p0), __builtin_bit_cast(bf16x8, vb0), acc, 0, 0, 0);
            acc = __builtin_amdgcn_mfma_f32_32x32x16_bf16(
                __builtin_bit_cast(bf16x8, p1), __builtin_bit_cast(bf16x8, vb1), acc, 0, 0, 0);
            __builtin_amdgcn_s_setprio(0);
        }
        __syncthreads();
    }

    if (grp != 0) {
#pragma unroll
        for (int r = 0; r < 16; ++r) redacc[((grp - 1) * 16 + r) * 128 + tl] = acc[r];
        redden[(grp - 1) * 128 + tl] = den;
    }
    __syncthreads();
    if (grp == 0) {
#pragma unroll
        for (int r = 0; r < 16; ++r)
            acc[r] += redacc[r * 128 + tl] + redacc[(16 + r) * 128 + tl] + redacc[(32 + r) * 128 + tl];
        den += redden[tl] + redden[128 + tl] + redden[256 + tl];
        const float dfull = den + __shfl_xor(den, 32);
        if (hi == 0) invs[w * 32 + lo] = 1.f / dfull;
        float4 i0 = *(const float4*)&invs[w * 32 + 4 * hi];
        float4 i1 = *(const float4*)&invs[w * 32 + 8 + 4 * hi];
        float4 i2 = *(const float4*)&invs[w * 32 + 16 + 4 * hi];
        float4 i3 = *(const float4*)&invs[w * 32 + 24 + 4 * hi];
        float iv[16] = {i0.x,i0.y,i0.z,i0.w, i1.x,i1.y,i1.z,i1.w,
                        i2.x,i2.y,i2.z,i2.w, i3.x,i3.y,i3.z,i3.w};
        const int b = bh >> 3, h = bh & 7;
        unsigned short* cbase = ctxb + ((size_t)(b * SQL + qc * 64 + w * 32)) * 256 + h * 32 + lo;
#pragma unroll
        for (int r = 0; r < 16; ++r) {
            const int qr = (r & 3) + 8 * (r >> 2) + 4 * hi;
            cbase[(size_t)qr * 256] = bfu(acc[r] * iv[r]);
        }
    }
}

// ---------------- fused GEMM(BM=64,BN=256) + bias + residual + LayerNorm ----------------
// TPL: KDIM (A stride & K), RES_BF (residual is bf16 ptr else f32), OUT_BF (write bf16 else f32)
template<int KDIM, int RES_BF, int OUT_BF>
__global__ __launch_bounds__(256, 2) void k_gemm_ln(
    const unsigned short* __restrict__ A, const unsigned short* __restrict__ Bt,
    const float* __restrict__ bias, const void* __restrict__ resid,
    const float* __restrict__ g, const float* __restrict__ bt,
    float* __restrict__ outf, unsigned short* __restrict__ outb)
{
    __shared__ __align__(16) char As[8192];    // 64 x 64k bf16
    __shared__ __align__(16) char Bs[32768];   // 256 x 64k bf16
    __shared__ float lnred[64][4];             // [row][wn*2 + {s,ss}]
    const int t = threadIdx.x;
    const int lane = t & 63, w = t >> 6;
    const int lo = lane & 31, hi = lane >> 5;
    const int wm = w & 1, wn = w >> 1;
    const int row0 = blockIdx.x * 64;
    f32x16 acc[4] = {};

    for (int kt = 0; kt < KDIM / 64; ++kt) {
        const int k0 = kt * 64;
#pragma unroll
        for (int it = 0; it < 2; ++it) {
            const int idx = it * 256 + t;
            const int r = idx >> 3, gg = idx & 7;
            glds16((const char*)(A + (size_t)(row0 + r) * KDIM + k0) + ((gg ^ (r & 7)) << 4),
                   As + idx * 16);
        }
#pragma unroll
        for (int it = 0; it < 8; ++it) {
            const int idx = it * 256 + t;
            const int r = idx >> 3, gg = idx & 7;
            glds16((const char*)(Bt + (size_t)r * KDIM + k0) + ((gg ^ (r & 7)) << 4),
                   Bs + idx * 16);
        }
        __syncthreads();
        const int rA = wm * 32 + lo;
#pragma unroll
        for (int s = 0; s < 4; ++s) {
            const int gg = s * 2 + hi;
            bf16x8 fa = *(const bf16x8*)(As + rA * 128 + ((gg ^ (rA & 7)) << 4));
#pragma unroll
            for (int n = 0; n < 4; ++n) {
                const int rB = wn * 128 + n * 32 + lo;
                bf16x8 fb = *(const bf16x8*)(Bs + rB * 128 + ((gg ^ (rB & 7)) << 4));
                acc[n] = __builtin_amdgcn_mfma_f32_32x32x16_bf16(fa, fb, acc[n], 0, 0, 0);
            }
        }
        __syncthreads();
    }

    // epilogue: bias + residual, row stats, LN
    float vals[4][16];
    float s_[16], ss_[16];
#pragma unroll
    for (int r = 0; r < 16; ++r) { s_[r] = 0.f; ss_[r] = 0.f; }
#pragma unroll
    for (int n = 0; n < 4; ++n) {
        const int c = wn * 128 + n * 32 + lo;
        const float bv = bias[c];
#pragma unroll
        for (int r = 0; r < 16; ++r) {
            const int gr = row0 + wm * 32 + (r & 3) + 8 * (r >> 2) + 4 * hi;
            float rv;
            if (RES_BF) rv = b2f(((const unsigned short*)resid)[(size_t)gr * 256 + c]);
            else        rv = ((const float*)resid)[(size_t)gr * 256 + c];
            float v = acc[n][r] + bv + rv;
            vals[n][r] = v;
            s_[r] += v; ss_[r] += v * v;
        }
    }
#pragma unroll
    for (int r = 0; r < 16; ++r) {
#pragma unroll
        for (int off = 16; off; off >>= 1) {
            s_[r]  += __shfl_xor(s_[r],  off);
            ss_[r] += __shfl_xor(ss_[r], off);
        }
    }
    if (lo == 0) {
#pragma unroll
        for (int r = 0; r < 16; ++r) {
            const int row = wm * 32 + (r & 3) + 8 * (r >> 2) + 4 * hi;
            lnred[row][wn * 2]     = s_[r];
            lnred[row][wn * 2 + 1] = ss_[r];
        }
    }
    __syncthreads();
    float mu_[16], rs_[16];
#pragma unroll
    for (int r = 0; r < 16; ++r) {
        const int row = wm * 32 + (r & 3) + 8 * (r >> 2) + 4 * hi;
        const float mu = (lnred[row][0] + lnred[row][2]) * (1.f / 256.f);
        const float va = (lnred[row][1] + lnred[row][3]) * (1.f / 256.f) - mu * mu;
        mu_[r] = mu; rs_[r] = rsqrtf(va + LNEPS);
    }
#pragma unroll
    for (int n = 0; n < 4; ++n) {
        const int c = wn * 128 + n * 32 + lo;
        const float gv = g[c], bv = bt[c];
#pragma unroll
        for (int r = 0; r < 16; ++r) {
            const int gr = row0 + wm * 32 + (r & 3) + 8 * (r >> 2) + 4 * hi;
            const float o = (vals[n][r] - mu_[r]) * rs_[r] * gv + bv;
            if (OUT_BF) outb[(size_t)gr * 256 + c] = bfu(o);
            else        outf[(size_t)gr * 256 + c] = o;
        }
    }
}

// ---------------- plain GEMM (ffn1): 64x128 tile ----------------
template<int KSTRIDE, int KT, int NFULL, int RELU>
__global__ __launch_bounds__(256, 6) void k_gemm(
    const unsigned short* __restrict__ A, const unsigned short* __restrict__ Bt,
    const float* __restrict__ bias, unsigned short* __restrict__ outb)
{
    __shared__ __align__(16) char As[8192];
    __shared__ __align__(16) char Bs[16384];
    const int t = threadIdx.x;
    const int lane = t & 63, w = t >> 6;
    const int lo = lane & 31, hi = lane >> 5;
    const int row0 = blockIdx.x * 64;
    const int col0 = blockIdx.y * 128;
    const int mr = (w & 1) * 32, nc = (w >> 1) * 64;
    f32x16 acc[2] = {};

    for (int kt = 0; kt < KT; ++kt) {
        const int k0 = kt * 64;
#pragma unroll
        for (int it = 0; it < 2; ++it) {
            const int idx = it * 256 + t;
            const int r = idx >> 3, g = idx & 7;
            glds16((const char*)(A + (size_t)(row0 + r) * KSTRIDE + k0) + ((g ^ (r & 7)) << 4),
                   As + idx * 16);
        }
#pragma unroll
        for (int it = 0; it < 4; ++it) {
            const int idx = it * 256 + t;
            const int r = idx >> 3, g = idx & 7;
            glds16((const char*)(Bt + (size_t)(col0 + r) * KSTRIDE + k0) + ((g ^ (r & 7)) << 4),
                   Bs + idx * 16);
        }
        __syncthreads();
        const int rA = mr + lo;
        const int rB = nc + lo;
#pragma unroll
        for (int s = 0; s < 4; ++s) {
            const int g = s * 2 + hi;
            bf16x8 fa  = *(const bf16x8*)(As + rA * 128 + ((g ^ (rA & 7)) << 4));
            bf16x8 fb0 = *(const bf16x8*)(Bs + rB * 128 + ((g ^ (rB & 7)) << 4));
            bf16x8 fb1 = *(const bf16x8*)(Bs + (rB + 32) * 128 + ((g ^ (rB & 7)) << 4));
            acc[0] = __builtin_amdgcn_mfma_f32_32x32x16_bf16(fa, fb0, acc[0], 0, 0, 0);
            acc[1] = __builtin_amdgcn_mfma_f32_32x32x16_bf16(fa, fb1, acc[1], 0, 0, 0);
        }
        __syncthreads();
    }
#pragma unroll
    for (int n = 0; n < 2; ++n) {
        const int c0 = col0 + nc + n * 32;
        const float bv = bias[c0 + lo];
#pragma unroll
        for (int r = 0; r < 16; ++r) {
            const int gr = row0 + mr + (r & 3) + 8 * (r >> 2) + 4 * hi;
            float vv = acc[n][r] + bv;
            if (RELU) vv = fmaxf(vv, 0.f);
            outb[(size_t)gr * NFULL + c0 + lo] = bfu(vv);
        }
    }
}

extern "C" void kernel_launch(void* const* d_in, const int* in_sizes, int n_in,
                              void* d_out, int out_size, void* d_ws, size_t ws_size,
                              hipStream_t stream) {
    const float* x   = (const float*)d_in[0];
    const float* wq  = (const float*)d_in[1];  const float* bq  = (const float*)d_in[2];
    const float* wk  = (const float*)d_in[3];  const float* bk  = (const float*)d_in[4];
    const float* wv  = (const float*)d_in[5];  const float* bv  = (const float*)d_in[6];
    const float* wo  = (const float*)d_in[7];  const float* wob = (const float*)d_in[8];
    const float* w1  = (const float*)d_in[9];  const float* b1  = (const float*)d_in[10];
    const float* w2  = (const float*)d_in[11]; const float* b2  = (const float*)d_in[12];
    const float* g1  = (const float*)d_in[13]; const float* bl1 = (const float*)d_in[14];
    const float* g2  = (const float*)d_in[15]; const float* bl2 = (const float*)d_in[16];

    char* ws = (char*)d_ws;
    unsigned short* xb    = (unsigned short*)(ws + B_XB);
    unsigned short* qb    = (unsigned short*)(ws + B_QB);
    unsigned short* kbuf  = (unsigned short*)(ws + B_KB);
    char*           vt    = (char*)(ws + B_VT);
    unsigned short* ctxb  = (unsigned short*)(ws + B_CTX);
    unsigned short* o1b   = (unsigned short*)(ws + B_O1B);
    unsigned short* mid   = (unsigned short*)(ws + B_MID);
    unsigned short* wqkvT = (unsigned short*)(ws + B_WQKVT);
    unsigned short* woT   = (unsigned short*)(ws + B_WOT);
    unsigned short* w1T   = (unsigned short*)(ws + B_W1T);
    unsigned short* w2T   = (unsigned short*)(ws + B_W2T);
    float* bqkv = (float*)(ws + B_BQKV);
    unsigned int* hqp = (unsigned int*)(ws + B_HQ);
    unsigned int* hkp = (unsigned int*)(ws + B_HK);
    float* out  = (float*)d_out;

    k_packall<<<dim3(2819), dim3(256), 0, stream>>>(wq, wk, wv, wo, w1, w2, bq, bk, bv, x,
                                                    wqkvT, woT, w1T, w2T, bqkv, xb);
    k_qkv<<<dim3(128, 6), dim3(256), 0, stream>>>(xb, wqkvT, bqkv, qb, kbuf, vt, hqp, hkp);
    k_attn<<<dim3(1024), dim3(512), 0, stream>>>(qb, kbuf, vt, hqp, hkp, ctxb);
    // out1 = LN1(x + ctx@wo + wob)  -> o1b (bf16)
    k_gemm_ln<256, 0, 1><<<dim3(128), dim3(256), 0, stream>>>(
        ctxb, woT, wob, x, g1, bl1, nullptr, o1b);
    // mid = relu(out1 @ w1 + b1)
    k_gemm<256, 4, 1024, 1><<<dim3(128, 8), dim3(256), 0, stream>>>(o1b, w1T, b1, mid);
    // out = LN2(out1 + mid@w2 + b2) -> f32
    k_gemm_ln<1024, 1, 0><<<dim3(128), dim3(256), 0, stream>>>(
        mid, w2T, b2, o1b, g2, bl2, out, nullptr);
}